// Round 3
// baseline (726.001 us; speedup 1.0000x reference)
//
#include <hip/hip_runtime.h>
#include <hip/hip_bf16.h>

// NaryTreeLSTM  B=32768, K=4, I=256, H=256
// DTYPE MODEL (round-2 forensics):
//   - inputs fp32-formatted on device (round-1: reading them as bf16 => NaN)
//   - OUTPUTS fp32 (round-2: absmax 2.236 > 2 impossible with bf16 h-stores;
//     exactly explained by bf16-pair-packing read back as fp32)
//   - threshold is bf16-scale (3.86e-2) => bf16 compute pipeline is fine.
// Pipeline: load fp32 -> cvt bf16 -> MFMA (fp32 accum) -> store fp32.
//
// ws layout:
//   cc   [B*K][H] bf16   child cell states
//   hsum [B][H]   bf16   sum_k child hidden
//   bf16 weight copies: Wi,Wf,Wo,Wu (H*I), Ui,Uo,Uu (H*H), WfK (K*H*H)
// total ~85.3 MB

#define BB 32768
#define KK 4
#define II 256
#define HH 256

typedef __bf16 bf16x8 __attribute__((ext_vector_type(8)));
typedef __bf16 bf16x4 __attribute__((ext_vector_type(4)));
typedef float f32x4 __attribute__((ext_vector_type(4)));

#define MFMA16(a, b, c) __builtin_amdgcn_mfma_f32_16x16x32_bf16(a, b, c, 0, 0, 0)

static __device__ __forceinline__ float fsig(float x) {
    return 1.0f / (1.0f + __expf(-x));
}
// tanh(x) = 1 - 2/(exp(2x)+1): saturates correctly at both extremes
static __device__ __forceinline__ float ftanhf(float x) {
    float e = __expf(2.0f * x);
    return 1.0f - 2.0f / (e + 1.0f);
}

static __device__ __forceinline__ bf16x8 cvt8(const float* __restrict__ p) {
    float4 f0 = ((const float4*)p)[0];
    float4 f1 = ((const float4*)p)[1];
    bf16x8 v;
    v[0] = (__bf16)f0.x; v[1] = (__bf16)f0.y; v[2] = (__bf16)f0.z; v[3] = (__bf16)f0.w;
    v[4] = (__bf16)f1.x; v[5] = (__bf16)f1.y; v[6] = (__bf16)f1.z; v[7] = (__bf16)f1.w;
    return v;
}

// ---------------- Kernel 0: fp32 -> bf16 weight conversion ----------------
struct CvtArgs {
    const float* src[8];
    __bf16* dst[8];
    int n[8];
};
__global__ __launch_bounds__(256) void cvt_k(CvtArgs a) {
    const int t = blockIdx.y;
    const int i = (blockIdx.x * 256 + threadIdx.x) * 4;
    if (i < a.n[t]) {
        float4 f = *(const float4*)(a.src[t] + i);
        bf16x4 v;
        v[0] = (__bf16)f.x; v[1] = (__bf16)f.y; v[2] = (__bf16)f.z; v[3] = (__bf16)f.w;
        *(bf16x4*)(a.dst[t] + i) = v;
    }
}

// ---------------- Kernel 1: child (leaf) gates ----------------
// Per child row r=b*4+k: ci=sig(cx@Wi.T+bi), co=sig(..Wo..), cu=tanh(..Wu..)
// cc[r]=ci*cu; hsum[b]=sum_k co*tanh(cc). Wave = 32 child rows (2 MFMA tiles).
// D-layout (row=quad*4+r, col=lane&15): one lane's 4 acc regs = the 4 children
// of one b-row -> hsum is 3 in-lane adds, no cross-lane traffic.
__global__ __launch_bounds__(256) void child_gates_k(
    const float* __restrict__ child_x,
    const __bf16* __restrict__ Wi, const __bf16* __restrict__ Wo,
    const __bf16* __restrict__ Wu,
    const float* __restrict__ bi, const float* __restrict__ bo,
    const float* __restrict__ bu,
    __bf16* __restrict__ cc, __bf16* __restrict__ hsum)
{
    const int lane = threadIdx.x & 63;
    const int wave = threadIdx.x >> 6;
    const int l16  = lane & 15;
    const int quad = lane >> 4;
    const int wbase = blockIdx.x * 128 + wave * 32;  // child-row base for wave

    // A[m=l16][k=quad*8+j], fp32 loads converted to bf16 fragments
    bf16x8 a[2][8];
#pragma unroll
    for (int t = 0; t < 2; ++t) {
        const float* rp = child_x + (size_t)(wbase + t * 16 + l16) * II + quad * 8;
#pragma unroll
        for (int ks = 0; ks < 8; ++ks)
            a[t][ks] = cvt8(rp + ks * 32);
    }

    for (int ct = 0; ct < 16; ++ct) {
        const int n = ct * 16 + l16;
        const float bin = bi[n], bon = bo[n], bun = bu[n];
        const int wo = n * II + quad * 8;  // B[k][n] = W[n][k]: contiguous 16B
        f32x4 ai[2] = {{0.f,0.f,0.f,0.f},{0.f,0.f,0.f,0.f}};
        f32x4 ao[2] = {{0.f,0.f,0.f,0.f},{0.f,0.f,0.f,0.f}};
        f32x4 au[2] = {{0.f,0.f,0.f,0.f},{0.f,0.f,0.f,0.f}};
#pragma unroll
        for (int ks = 0; ks < 8; ++ks) {
            bf16x8 bwi = *(const bf16x8*)(Wi + wo + ks * 32);
            bf16x8 bwo = *(const bf16x8*)(Wo + wo + ks * 32);
            bf16x8 bwu = *(const bf16x8*)(Wu + wo + ks * 32);
#pragma unroll
            for (int t = 0; t < 2; ++t) {
                ai[t] = MFMA16(a[t][ks], bwi, ai[t]);
                ao[t] = MFMA16(a[t][ks], bwo, ao[t]);
                au[t] = MFMA16(a[t][ks], bwu, au[t]);
            }
        }
#pragma unroll
        for (int t = 0; t < 2; ++t) {
            const int crb = wbase + t * 16 + quad * 4;  // child row of reg r=0
            float chs = 0.f;
#pragma unroll
            for (int r = 0; r < 4; ++r) {
                float civ = fsig(ai[t][r] + bin);
                float cov = fsig(ao[t][r] + bon);
                float cuv = ftanhf(au[t][r] + bun);
                float ccv = civ * cuv;
                chs += cov * ftanhf(ccv);
                cc[(size_t)(crb + r) * HH + n] = (__bf16)ccv;
            }
            hsum[(size_t)(crb >> 2) * HH + n] = (__bf16)chs;
        }
    }
}

// ---------------- Kernel 2: root (node) gates ----------------
// i=sig(x@Wi.T+bi+hsum@Ui.T), o,u analogous; f_k=sig(x@Wf.T+bf+hsum@WfK_k.T)
// c=i*u+sum_k f_k*cc_k; h=o*tanh(c). Wave = 32 b-rows (2 tiles) to halve
// weight rereads. Gates in 2 passes (i/o/u then f's) to cap live VGPRs.
__global__ __launch_bounds__(256) void root_k(
    const float* __restrict__ x,
    const __bf16* __restrict__ Wi, const __bf16* __restrict__ Wf,
    const __bf16* __restrict__ Wo, const __bf16* __restrict__ Wu,
    const __bf16* __restrict__ Ui, const __bf16* __restrict__ Uo,
    const __bf16* __restrict__ Uu, const __bf16* __restrict__ WfK,
    const float* __restrict__ bi, const float* __restrict__ bf_,
    const float* __restrict__ bo, const float* __restrict__ bu,
    const __bf16* __restrict__ cc, const __bf16* __restrict__ hsum,
    float* __restrict__ out)
{
    const int lane = threadIdx.x & 63;
    const int wave = threadIdx.x >> 6;
    const int l16  = lane & 15;
    const int quad = lane >> 4;
    const int rbase = blockIdx.x * 128 + wave * 32;  // b-row base of wave

    bf16x8 ax[2][8], ah[2][8];
#pragma unroll
    for (int t = 0; t < 2; ++t) {
        const float*  xp = x    + (size_t)(rbase + t * 16 + l16) * II + quad * 8;
        const __bf16* hp = hsum + (size_t)(rbase + t * 16 + l16) * HH + quad * 8;
#pragma unroll
        for (int ks = 0; ks < 8; ++ks) {
            ax[t][ks] = cvt8(xp + ks * 32);
            ah[t][ks] = *(const bf16x8*)(hp + ks * 32);
        }
    }

    for (int ct = 0; ct < 16; ++ct) {
        const int n = ct * 16 + l16;
        const float bin = bi[n], bfn = bf_[n], bon = bo[n], bun = bu[n];
        const int wo = n * II + quad * 8;

        // ---- pass 1: i, o, u ----
        f32x4 ai[2] = {{0.f,0.f,0.f,0.f},{0.f,0.f,0.f,0.f}};
        f32x4 ao[2] = {{0.f,0.f,0.f,0.f},{0.f,0.f,0.f,0.f}};
        f32x4 au[2] = {{0.f,0.f,0.f,0.f},{0.f,0.f,0.f,0.f}};
#pragma unroll
        for (int ks = 0; ks < 8; ++ks) {
            const int o = wo + ks * 32;
            bf16x8 bwi = *(const bf16x8*)(Wi + o);
            bf16x8 bui = *(const bf16x8*)(Ui + o);
            bf16x8 bwo = *(const bf16x8*)(Wo + o);
            bf16x8 buo = *(const bf16x8*)(Uo + o);
            bf16x8 bwu = *(const bf16x8*)(Wu + o);
            bf16x8 buu = *(const bf16x8*)(Uu + o);
#pragma unroll
            for (int t = 0; t < 2; ++t) {
                ai[t] = MFMA16(ax[t][ks], bwi, ai[t]);
                ai[t] = MFMA16(ah[t][ks], bui, ai[t]);
                ao[t] = MFMA16(ax[t][ks], bwo, ao[t]);
                ao[t] = MFMA16(ah[t][ks], buo, ao[t]);
                au[t] = MFMA16(ax[t][ks], bwu, au[t]);
                au[t] = MFMA16(ah[t][ks], buu, au[t]);
            }
        }
        float iv[2][4], ov[2][4], uv[2][4];
#pragma unroll
        for (int t = 0; t < 2; ++t)
#pragma unroll
            for (int r = 0; r < 4; ++r) {
                iv[t][r] = fsig(ai[t][r] + bin);
                ov[t][r] = fsig(ao[t][r] + bon);
                uv[t][r] = ftanhf(au[t][r] + bun);
            }

        // ---- pass 2: f-family ----
        f32x4 axf[2] = {{0.f,0.f,0.f,0.f},{0.f,0.f,0.f,0.f}};
        f32x4 af[4][2] = {{{0.f,0.f,0.f,0.f},{0.f,0.f,0.f,0.f}},
                          {{0.f,0.f,0.f,0.f},{0.f,0.f,0.f,0.f}},
                          {{0.f,0.f,0.f,0.f},{0.f,0.f,0.f,0.f}},
                          {{0.f,0.f,0.f,0.f},{0.f,0.f,0.f,0.f}}};
#pragma unroll
        for (int ks = 0; ks < 8; ++ks) {
            const int o = wo + ks * 32;
            bf16x8 bwf = *(const bf16x8*)(Wf + o);
            bf16x8 bk0 = *(const bf16x8*)(WfK + 0 * HH * II + o);
            bf16x8 bk1 = *(const bf16x8*)(WfK + 1 * HH * II + o);
            bf16x8 bk2 = *(const bf16x8*)(WfK + 2 * HH * II + o);
            bf16x8 bk3 = *(const bf16x8*)(WfK + 3 * HH * II + o);
#pragma unroll
            for (int t = 0; t < 2; ++t) {
                axf[t]   = MFMA16(ax[t][ks], bwf, axf[t]);
                af[0][t] = MFMA16(ah[t][ks], bk0, af[0][t]);
                af[1][t] = MFMA16(ah[t][ks], bk1, af[1][t]);
                af[2][t] = MFMA16(ah[t][ks], bk2, af[2][t]);
                af[3][t] = MFMA16(ah[t][ks], bk3, af[3][t]);
            }
        }

        // ---- epilogue (fp32 stores) ----
#pragma unroll
        for (int t = 0; t < 2; ++t)
#pragma unroll
            for (int r = 0; r < 4; ++r) {
                const int b = rbase + t * 16 + quad * 4 + r;
                const float xfv = axf[t][r] + bfn;
                float cv = iv[t][r] * uv[t][r];
#pragma unroll
                for (int k = 0; k < 4; ++k) {
                    float fv = fsig(xfv + af[k][t][r]);
                    cv += fv * (float)cc[(size_t)(b * 4 + k) * HH + n];
                }
                float hv = ov[t][r] * ftanhf(cv);
                out[(size_t)b * HH + n] = hv;                    // h
                out[(size_t)BB * HH + (size_t)b * HH + n] = cv;  // c
            }
    }
}

extern "C" void kernel_launch(void* const* d_in, const int* in_sizes, int n_in,
                              void* d_out, int out_size, void* d_ws, size_t ws_size,
                              hipStream_t stream) {
    const float* x    = (const float*)d_in[0];
    const float* cx   = (const float*)d_in[1];
    const float* Wi   = (const float*)d_in[2];
    const float* bi   = (const float*)d_in[3];
    const float* Wf   = (const float*)d_in[4];
    const float* bf_  = (const float*)d_in[5];
    const float* Wo   = (const float*)d_in[6];
    const float* bo   = (const float*)d_in[7];
    const float* Wu   = (const float*)d_in[8];
    const float* bu   = (const float*)d_in[9];
    const float* Ui   = (const float*)d_in[10];
    const float* Uo   = (const float*)d_in[11];
    const float* Uu   = (const float*)d_in[12];
    const float* WfK  = (const float*)d_in[13];

    __bf16* cc = (__bf16*)d_ws;                     // [B*K][H]
    __bf16* hs = cc + (size_t)BB * KK * HH;         // [B][H]
    __bf16* wb = hs + (size_t)BB * HH;              // bf16 weight block
    __bf16 *Wi_b = wb,            *Wf_b = Wi_b + HH * II, *Wo_b = Wf_b + HH * II,
           *Wu_b = Wo_b + HH * II, *Ui_b = Wu_b + HH * II, *Uo_b = Ui_b + HH * HH,
           *Uu_b = Uo_b + HH * HH, *WfK_b = Uu_b + HH * HH;  // WfK: K*H*H

    CvtArgs ca;
    ca.src[0] = Wi;  ca.dst[0] = Wi_b;  ca.n[0] = HH * II;
    ca.src[1] = Wf;  ca.dst[1] = Wf_b;  ca.n[1] = HH * II;
    ca.src[2] = Wo;  ca.dst[2] = Wo_b;  ca.n[2] = HH * II;
    ca.src[3] = Wu;  ca.dst[3] = Wu_b;  ca.n[3] = HH * II;
    ca.src[4] = Ui;  ca.dst[4] = Ui_b;  ca.n[4] = HH * HH;
    ca.src[5] = Uo;  ca.dst[5] = Uo_b;  ca.n[5] = HH * HH;
    ca.src[6] = Uu;  ca.dst[6] = Uu_b;  ca.n[6] = HH * HH;
    ca.src[7] = WfK; ca.dst[7] = WfK_b; ca.n[7] = KK * HH * HH;

    cvt_k<<<dim3(KK * HH * HH / 1024, 8), dim3(256), 0, stream>>>(ca);
    child_gates_k<<<dim3(BB * KK / 128), dim3(256), 0, stream>>>(
        cx, Wi_b, Wo_b, Wu_b, bi, bo, bu, cc, hs);
    root_k<<<dim3(BB / 128), dim3(256), 0, stream>>>(
        x, Wi_b, Wf_b, Wo_b, Wu_b, Ui_b, Uo_b, Uu_b, WfK_b,
        bi, bf_, bo, bu, cc, hs, (float*)d_out);
}